// Round 11
// baseline (83.544 us; speedup 1.0000x reference)
//
#include <hip/hip_runtime.h>
#include <stdint.h>

// GCMConv on MI355X. Data model (verified rounds 0-3):
//   x      : float32 (1,16384,8,3,3,2)  — complex pair = v2f
//   weight : float32 (4,9,33)
//   out    : float32 (1,16384,8,3,3,2)
//
// Round-11: 32 threads/site (u=out-channel, h=v-channel 0..7).
//   M[u,h] = sum_w16 ( wt[u,h,w16] t[w16] + wt[u,h,16+w16] t[w16]^+ ) + wt[u,h,32] I
//   cc     = A @ M[u,h],  A = (h<4) ? w[h] : w[h-4]^+
//   v=8 channel (identity): each thread adds its 2-w16 share directly to cc.
//   reduce cc over h via shfl_xor(1,2,4); h==0 stores.
// Packed fp32 forced via ext_vector_type + __builtin_elementwise_fma
// (llvm.fma.v2f32 -> v_pk_fma_f32). Live set ~95 floats -> 4+ waves/SIMD.

typedef float v2f __attribute__((ext_vector_type(2)));

#define SPB 8             // sites per block
#define TPB 256           // 32 threads per site
#define NSITES 16384
#define TS2_SITE 146      // v2f units per site: 16*9 + 2 pad
#define NWGT 1188         // 4*9*33

#if defined(__has_builtin)
#if __has_builtin(__builtin_elementwise_fma)
#define HAVE_EW_FMA 1
#endif
#endif

__device__ __forceinline__ v2f pkfma(v2f a, v2f b, v2f c){
#ifdef HAVE_EW_FMA
    return __builtin_elementwise_fma(a, b, c);
#else
    v2f r; r.x = fmaf(a.x, b.x, c.x); r.y = fmaf(a.y, b.y, c.y); return r;
#endif
}
__device__ __forceinline__ v2f spl(float s){ return (v2f){s, s}; }
__device__ __forceinline__ v2f pn (float s){ return (v2f){s, -s}; }
__device__ __forceinline__ v2f np (float s){ return (v2f){-s, s}; }
__device__ __forceinline__ v2f swp(v2f a){ return __builtin_shufflevector(a, a, 1, 0); }
__device__ __forceinline__ v2f zero2(){ return (v2f){0.f, 0.f}; }

__device__ __forceinline__ int neigh(int s, int a){
    // dims (8,8,16,16): d3 bits[0:4), d2 bits[4:8), d1 bits[8:11), d0 bits[11:14)
    if (a == 3) return (s & ~15)        | ((s + 1)    & 15);
    if (a == 2) return (s & ~(15 << 4)) | ((s + 16)   & (15 << 4));
    if (a == 1) return (s & ~(7 << 8))  | ((s + 256)  & (7 << 8));
    return              (s & ~(7 << 11))| ((s + 2048) & (7 << 11));
}

__global__ __launch_bounds__(TPB, 3)
void gcm_fused(const float* __restrict__ xp,
               const float* __restrict__ wgt,
               float* __restrict__ outp)
{
    __shared__ v2f lt[SPB * TS2_SITE];
    __shared__ float wsm[NWGT];
    const v2f* x2 = (const v2f*)xp;
    v2f* o2 = (v2f*)outp;

    const int tid = threadIdx.x;
    const int h   = tid & 7;            // v-channel; lane bits 0-2 -> shfl reduce
    const int u   = (tid >> 3) & 3;     // output channel / phase1 axis
    const int sl  = tid >> 5;           // site within block
    const int s   = blockIdx.x * SPB + sl;
    const int g   = h & 3;

    // stage weights to LDS
    #pragma unroll 1
    for (int idx = tid; idx < NWGT; idx += TPB) wsm[idx] = wgt[idx];

    // ============ phase 1: transports on h<4 threads: t[u*4+h] = U_u W_h(s+u^) U_u^+
    if (h < 4){
        v2f uc[9], wc[9];
        {
            const v2f* up = x2 + (s * 8 + u) * 9;
            #pragma unroll
            for (int e = 0; e < 9; e++) uc[e] = up[e];
        }
        const int sn = neigh(s, u);
        {
            const v2f* wp = x2 + (sn * 8 + 4 + h) * 9;
            #pragma unroll
            for (int e = 0; e < 9; e++) wc[e] = wp[e];
        }
        // T1 = U * W
        v2f t1[9];
        #pragma unroll
        for (int r = 0; r < 3; r++){
            #pragma unroll
            for (int k = 0; k < 3; k++){
                v2f acc = zero2();
                #pragma unroll
                for (int j = 0; j < 3; j++){
                    v2f a_ = uc[r*3+j], b_ = wc[j*3+k];
                    acc = pkfma(spl(a_.x), b_, acc);
                    acc = pkfma(np(a_.y), swp(b_), acc);
                }
                t1[r*3+k] = acc;
            }
        }
        // T = T1 * U^+ : T[r,k] = sum_j T1[r,j] * conj(U[k,j])
        v2f* dst = &lt[sl * TS2_SITE + (u * 4 + h) * 9];
        #pragma unroll
        for (int r = 0; r < 3; r++){
            #pragma unroll
            for (int k = 0; k < 3; k++){
                v2f acc = zero2();
                #pragma unroll
                for (int j = 0; j < 3; j++){
                    v2f a_ = t1[r*3+j], b_ = uc[k*3+j];
                    acc = pkfma(pn(a_.x), b_, acc);
                    acc = pkfma(spl(a_.y), swp(b_), acc);
                }
                dst[r*3+k] = acc;
            }
        }
    } else if (h == 4){
        // pass-through copy of u channel
        const v2f* src = x2 + (s * 8 + u) * 9;
        v2f* dst = o2 + (s * 8 + u) * 9;
        #pragma unroll
        for (int e = 0; e < 9; e++) dst[e] = src[e];
    }
    __syncthreads();

    // ============ phase 2: thread (u,h) builds M[u,h] ============
    v2f M[9], cc[9];
    #pragma unroll
    for (int e = 0; e < 9; e++){ M[e] = zero2(); cc[e] = zero2(); }

    const float* wu  = wsm + u * 297;    // weight[u][v][w], stride 33 per v
    const float* wvh = wu + h * 33;      // v = h
    const float* wu8 = wu + 8 * 33;      // v = 8

    const v2f* tbase = &lt[sl * TS2_SITE];

    // ---- M-build: rolled 16-iteration loop
    #pragma unroll 1
    for (int w16 = 0; w16 < 16; w16++){
        const v2f* tp = tbase + w16 * 9;
        v2f tc[9];
        #pragma unroll
        for (int e = 0; e < 9; e++) tc[e] = tp[e];
        float a = wvh[w16], b = wvh[16 + w16];
        #pragma unroll
        for (int i = 0; i < 3; i++){
            #pragma unroll
            for (int j = 0; j < 3; j++){
                const int e = i*3+j, eT = j*3+i;
                M[e] = pkfma(spl(a), tc[e],  M[e]);
                M[e] = pkfma(pn(b),  tc[eT], M[e]);
            }
        }
    }

    // ---- v=8 channel: this thread's 2-w16 share, added directly to cc
    #pragma unroll
    for (int q = 0; q < 2; q++){
        const int w16 = 2 * h + q;
        const v2f* tp = tbase + w16 * 9;
        v2f tc[9];
        #pragma unroll
        for (int e = 0; e < 9; e++) tc[e] = tp[e];
        float c8 = wu8[w16], d8 = wu8[16 + w16];
        #pragma unroll
        for (int i = 0; i < 3; i++){
            #pragma unroll
            for (int j = 0; j < 3; j++){
                const int e = i*3+j, eT = j*3+i;
                cc[e] = pkfma(spl(c8), tc[e],  cc[e]);
                cc[e] = pkfma(pn(d8),  tc[eT], cc[e]);
            }
        }
    }

    // ---- identity (w=32) contributions
    {
        float ch = wvh[32];
        M[0].x += ch; M[4].x += ch; M[8].x += ch;
        if (h == 0){
            float e8 = wu8[32];
            cc[0].x += e8; cc[4].x += e8; cc[8].x += e8;
        }
    }

    // ---- A = (h<4) ? w[g] : w[g]^+   (branchless select, static indices)
    v2f A[9];
    {
        const v2f* wp = x2 + (s * 8 + 4 + g) * 9;
        v2f wgr[9];
        #pragma unroll
        for (int e = 0; e < 9; e++) wgr[e] = wp[e];
        const bool dag = (h >= 4);
        #pragma unroll
        for (int i = 0; i < 3; i++){
            #pragma unroll
            for (int j = 0; j < 3; j++){
                v2f p = wgr[i*3+j];
                v2f q = wgr[j*3+i]; q.y = -q.y;
                A[i*3+j] = dag ? q : p;
            }
        }
    }

    // ---- cc += A @ M
    #pragma unroll
    for (int i = 0; i < 3; i++){
        #pragma unroll
        for (int k = 0; k < 3; k++){
            v2f acc = cc[i*3+k];
            #pragma unroll
            for (int j = 0; j < 3; j++){
                v2f a_ = A[i*3+j];
                v2f m  = M[j*3+k];
                acc = pkfma(spl(a_.x), m,      acc);   // (ax*mr, ax*mi)
                acc = pkfma(np(a_.y),  swp(m), acc);   // (-ay*mi, ay*mr)
            }
            cc[i*3+k] = acc;
        }
    }

    // ---- reduce over h (lane bits 0-2) and store
    #pragma unroll
    for (int e = 0; e < 9; e++){
        #pragma unroll
        for (int d = 1; d <= 4; d <<= 1){
            cc[e].x += __shfl_xor(cc[e].x, d);
            cc[e].y += __shfl_xor(cc[e].y, d);
        }
    }
    if (h == 0){
        v2f* dst = o2 + (s * 8 + 4 + u) * 9;
        #pragma unroll
        for (int e = 0; e < 9; e++) dst[e] = cc[e];
    }
}

extern "C" void kernel_launch(void* const* d_in, const int* in_sizes, int n_in,
                              void* d_out, int out_size, void* d_ws, size_t ws_size,
                              hipStream_t stream)
{
    const float* x = (const float*)d_in[0];
    const float* w = (const float*)d_in[1];
    float* out = (float*)d_out;
    dim3 grid(NSITES / SPB);
    dim3 block(TPB);
    hipLaunchKernelGGL(gcm_fused, grid, block, 0, stream, x, w, out);
}

// Round 12
// 76.719 us; speedup vs baseline: 1.0890x; 1.0890x over previous
//
#include <hip/hip_runtime.h>
#include <stdint.h>

// GCMConv on MI355X. Data model (verified rounds 0-3):
//   x      : float32 (1,16384,8,3,3,2)  — complex pair = v2f
//   weight : float32 (4,9,33)
//   out    : float32 (1,16384,8,3,3,2)
//
// M-factorization (R9/R10 base, 16 threads/site: u=out-channel, g=quarter):
//   M[u,v] = sum_w16 ( wt[u,v,w16] t[w16] + wt[u,v,16+w16] t[w16]^+ ) + wt[u,v,32] I
//   out[u] = sum_v w_full[v] @ M[u,v];  thread (u,g) builds M[u,g], M[u,4+g]
//   + predicated v=8 quarter; epilogue cc += w[g]@M1 + w[g]^+@M2; shfl_xor over g.
//
// Round-12: latency hiding. (a) register double-buffered t-tile ping-pong
// (ds_reads of tile k+1 in flight during FMAs of tile k); (b) wg global load
// issued BEFORE the M-loop (~900 cyc cold latency overlapped with compute).

typedef float v2f __attribute__((ext_vector_type(2)));

#define SPB 16            // sites per block
#define TPB 256           // 16 threads per site
#define NSITES 16384
#define TS2_SITE 146      // v2f units per site: 16*9 + 2 pad
#define NWGT 1188         // 4*9*33

#if defined(__has_builtin)
#if __has_builtin(__builtin_elementwise_fma)
#define HAVE_EW_FMA 1
#endif
#endif

__device__ __forceinline__ v2f pkfma(v2f a, v2f b, v2f c){
#ifdef HAVE_EW_FMA
    return __builtin_elementwise_fma(a, b, c);
#else
    v2f r; r.x = fmaf(a.x, b.x, c.x); r.y = fmaf(a.y, b.y, c.y); return r;
#endif
}
__device__ __forceinline__ v2f spl(float s){ return (v2f){s, s}; }
__device__ __forceinline__ v2f pn (float s){ return (v2f){s, -s}; }
__device__ __forceinline__ v2f np (float s){ return (v2f){-s, s}; }
__device__ __forceinline__ v2f swp(v2f a){ return __builtin_shufflevector(a, a, 1, 0); }
__device__ __forceinline__ v2f zero2(){ return (v2f){0.f, 0.f}; }

__device__ __forceinline__ int neigh(int s, int a){
    // dims (8,8,16,16): d3 bits[0:4), d2 bits[4:8), d1 bits[8:11), d0 bits[11:14)
    if (a == 3) return (s & ~15)        | ((s + 1)    & 15);
    if (a == 2) return (s & ~(15 << 4)) | ((s + 16)   & (15 << 4));
    if (a == 1) return (s & ~(7 << 8))  | ((s + 256)  & (7 << 8));
    return              (s & ~(7 << 11))| ((s + 2048) & (7 << 11));
}

struct Coefs { float a1, b1, a2, b2, c8, d8; };

__global__ __launch_bounds__(TPB, 2)
void gcm_fused(const float* __restrict__ xp,
               const float* __restrict__ wgt,
               float* __restrict__ outp)
{
    __shared__ v2f lt[SPB * TS2_SITE];
    __shared__ float wsm[NWGT];
    const v2f* x2 = (const v2f*)xp;
    v2f* o2 = (v2f*)outp;

    const int tid = threadIdx.x;
    const int g   = tid & 3;            // lane bits 0-1 -> shfl_xor reduction
    const int u   = (tid >> 2) & 3;     // output channel / phase1 axis
    const int sl  = tid >> 4;           // site within block
    const int s   = blockIdx.x * SPB + sl;

    // stage weights to LDS
    #pragma unroll 1
    for (int idx = tid; idx < NWGT; idx += TPB) wsm[idx] = wgt[idx];

    // ============ phase 1: one transport per thread: t[u*4+g] = U_u W_g(s+u^) U_u^+
    {
        v2f uc[9], wc[9];
        {
            const v2f* up = x2 + (s * 8 + u) * 9;
            #pragma unroll
            for (int e = 0; e < 9; e++) uc[e] = up[e];
        }
        const int sn = neigh(s, u);
        {
            const v2f* wp = x2 + (sn * 8 + 4 + g) * 9;
            #pragma unroll
            for (int e = 0; e < 9; e++) wc[e] = wp[e];
        }
        // T1 = U * W
        v2f t1[9];
        #pragma unroll
        for (int r = 0; r < 3; r++){
            #pragma unroll
            for (int k = 0; k < 3; k++){
                v2f acc = zero2();
                #pragma unroll
                for (int j = 0; j < 3; j++){
                    v2f a_ = uc[r*3+j], b_ = wc[j*3+k];
                    acc = pkfma(spl(a_.x), b_, acc);
                    acc = pkfma(np(a_.y), swp(b_), acc);
                }
                t1[r*3+k] = acc;
            }
        }
        // T = T1 * U^+ : T[r,k] = sum_j T1[r,j] * conj(U[k,j])
        v2f* dst = &lt[sl * TS2_SITE + (u * 4 + g) * 9];
        #pragma unroll
        for (int r = 0; r < 3; r++){
            #pragma unroll
            for (int k = 0; k < 3; k++){
                v2f acc = zero2();
                #pragma unroll
                for (int j = 0; j < 3; j++){
                    v2f a_ = t1[r*3+j], b_ = uc[k*3+j];
                    acc = pkfma(pn(a_.x), b_, acc);
                    acc = pkfma(spl(a_.y), swp(b_), acc);
                }
                dst[r*3+k] = acc;
            }
        }
    }
    __syncthreads();

    // ============ phase 2 ============
    // pass-through copy of u channels (one quarter of lanes)
    if (g == 1){
        const v2f* src = x2 + (s * 8 + u) * 9;
        v2f* dst = o2 + (s * 8 + u) * 9;
        #pragma unroll
        for (int e = 0; e < 9; e++) dst[e] = src[e];
    }

    // EARLY-ISSUE: own w[g] global load; consumed only in the epilogue,
    // so its ~900-cycle cold latency overlaps the whole M-build loop.
    v2f wg[9];
    {
        const v2f* wp = x2 + (s * 8 + 4 + g) * 9;
        #pragma unroll
        for (int e = 0; e < 9; e++) wg[e] = wp[e];
    }

    v2f M1[9], M2[9], cc[9];
    #pragma unroll
    for (int e = 0; e < 9; e++){
        M1[e] = zero2(); M2[e] = zero2(); cc[e] = zero2();
    }

    const float* wu  = wsm + u * 297;    // weight[u][v][w], stride 33 per v
    const float* wuA = wu + g * 33;      // v = g
    const float* wuB = wu + (4 + g) * 33;// v = 4+g
    const float* wu8 = wu + 8 * 33;      // v = 8

    const v2f* tbase = &lt[sl * TS2_SITE];

    // ---- M-build: register double-buffered ping-pong over 16 tiles ----
    v2f tA[9], tB[9];
    #pragma unroll
    for (int e = 0; e < 9; e++) tA[e] = tbase[e];          // tile 0

#define LOAD_TILE(dst, w)  { const v2f* _tp = tbase + (w) * 9; \
    _Pragma("unroll") for (int e = 0; e < 9; e++) dst[e] = _tp[e]; }

#define GET_COEF(C, w)  { C.a1 = wuA[w]; C.b1 = wuA[16 + (w)]; \
    C.a2 = wuB[w]; C.b2 = wuB[16 + (w)]; \
    const bool _m = (((w) >> 2) == g); \
    C.c8 = _m ? wu8[w] : 0.f; C.d8 = _m ? wu8[16 + (w)] : 0.f; }

#define COMPUTE(T, C) { _Pragma("unroll") for (int i = 0; i < 3; i++){ \
        _Pragma("unroll") for (int j = 0; j < 3; j++){ \
            const int e = i*3+j, eT = j*3+i; \
            M1[e] = pkfma(spl(C.a1), T[e],  M1[e]); \
            M1[e] = pkfma(pn(C.b1),  T[eT], M1[e]); \
            M2[e] = pkfma(spl(C.a2), T[e],  M2[e]); \
            M2[e] = pkfma(pn(C.b2),  T[eT], M2[e]); \
            cc[e] = pkfma(spl(C.c8), T[e],  cc[e]); \
            cc[e] = pkfma(pn(C.d8),  T[eT], cc[e]); } } }

    #pragma unroll 1
    for (int w16 = 0; w16 < 14; w16 += 2){
        Coefs cA; GET_COEF(cA, w16);
        LOAD_TILE(tB, w16 + 1);          // in flight during COMPUTE(tA)
        COMPUTE(tA, cA);
        Coefs cB; GET_COEF(cB, w16 + 1);
        LOAD_TILE(tA, w16 + 2);          // in flight during COMPUTE(tB)
        COMPUTE(tB, cB);
    }
    {   // tail: tiles 14, 15
        Coefs cA; GET_COEF(cA, 14);
        LOAD_TILE(tB, 15);
        COMPUTE(tA, cA);
        Coefs cB; GET_COEF(cB, 15);
        COMPUTE(tB, cB);
    }
#undef LOAD_TILE
#undef GET_COEF
#undef COMPUTE

    // ---- identity (w=32) contributions to the diagonals
    {
        float c1 = wuA[32], c2 = wuB[32];
        M1[0].x += c1; M1[4].x += c1; M1[8].x += c1;
        M2[0].x += c2; M2[4].x += c2; M2[8].x += c2;
        if (g == 0){
            float e8 = wu8[32];
            cc[0].x += e8; cc[4].x += e8; cc[8].x += e8;
        }
    }

    // ---- epilogue: cc += w[g] @ M1 + w[g]^+ @ M2
    #pragma unroll
    for (int i = 0; i < 3; i++){
        #pragma unroll
        for (int k = 0; k < 3; k++){
            v2f acc = cc[i*3+k];
            #pragma unroll
            for (int j = 0; j < 3; j++){
                v2f a_ = wg[i*3+j];
                v2f m  = M1[j*3+k];
                acc = pkfma(spl(a_.x), m,      acc);   // (ax*mr, ax*mi)
                acc = pkfma(np(a_.y),  swp(m), acc);   // (-ay*mi, ay*mr)
            }
            #pragma unroll
            for (int j = 0; j < 3; j++){
                v2f b_ = wg[j*3+i];                    // conj-transpose source
                v2f m  = M2[j*3+k];
                acc = pkfma(spl(b_.x), m,      acc);   // (bx*mr, bx*mi)
                acc = pkfma(pn(b_.y),  swp(m), acc);   // (by*mi, -by*mr)
            }
            cc[i*3+k] = acc;
        }
    }

    // --- reduce partials over g (lane bits 0-1) and store
    #pragma unroll
    for (int e = 0; e < 9; e++){
        cc[e].x += __shfl_xor(cc[e].x, 1);
        cc[e].x += __shfl_xor(cc[e].x, 2);
        cc[e].y += __shfl_xor(cc[e].y, 1);
        cc[e].y += __shfl_xor(cc[e].y, 2);
    }
    if (g == 0){
        v2f* dst = o2 + (s * 8 + 4 + u) * 9;
        #pragma unroll
        for (int e = 0; e < 9; e++) dst[e] = cc[e];
    }
}

extern "C" void kernel_launch(void* const* d_in, const int* in_sizes, int n_in,
                              void* d_out, int out_size, void* d_ws, size_t ws_size,
                              hipStream_t stream)
{
    const float* x = (const float*)d_in[0];
    const float* w = (const float*)d_in[1];
    float* out = (float*)d_out;
    dim3 grid(NSITES / SPB);
    dim3 block(TPB);
    hipLaunchKernelGGL(gcm_fused, grid, block, 0, stream, x, w, out);
}

// Round 13
// 75.523 us; speedup vs baseline: 1.1062x; 1.0158x over previous
//
#include <hip/hip_runtime.h>
#include <stdint.h>

// GCMConv on MI355X. Data model (verified rounds 0-3):
//   x      : float32 (1,16384,8,3,3,2)  — complex pair = v2f
//   weight : float32 (4,9,33)
//   out    : float32 (1,16384,8,3,3,2)
//
// M-factorization (16 threads/site: u=out-channel, g=quarter):
//   M[u,v] = sum_w16 ( wt[u,v,w16] t[w16] + wt[u,v,16+w16] t[w16]^+ ) + wt[u,v,32] I
//   out[u] = sum_v w_full[v] @ M[u,v];  thread (u,g) builds M[u,g], M[u,4+g];
//   cc gets the v=8 (identity-channel) share from the thread's own w16 quarter.
//
// Round-13 "minimum live set / minimum work":
//  - main loop: M1/M2 only (36 pk/iter, uniform tile index -> broadcast LDS reads)
//  - separate 4-iter cc loop over own quarter (kills 216 zero-FMAs, no divergence)
//  - no double-buffer, wg loaded late (R12 proved both neutral; frees 36 floats)
//  - 16B-aligned tiles (stride 10 v2f) + explicit float4 LDS ops -> ds_*_b128
// Peak live ~95 floats -> allocator lands <128 VGPR with zero scratch.

typedef float v2f __attribute__((ext_vector_type(2)));

#define SPB 16            // sites per block
#define TPB 256           // 16 threads per site
#define NSITES 16384
#define TS_TILE 10        // v2f per tile (9 + 1 pad, 80 B -> 16B-aligned tiles)
#define TS2_SITE 164      // v2f per site: 16*10 + 4 spare
#define NWGT 1188         // 4*9*33

#if defined(__has_builtin)
#if __has_builtin(__builtin_elementwise_fma)
#define HAVE_EW_FMA 1
#endif
#endif

__device__ __forceinline__ v2f pkfma(v2f a, v2f b, v2f c){
#ifdef HAVE_EW_FMA
    return __builtin_elementwise_fma(a, b, c);
#else
    v2f r; r.x = fmaf(a.x, b.x, c.x); r.y = fmaf(a.y, b.y, c.y); return r;
#endif
}
__device__ __forceinline__ v2f spl(float s){ return (v2f){s, s}; }
__device__ __forceinline__ v2f pn (float s){ return (v2f){s, -s}; }
__device__ __forceinline__ v2f np (float s){ return (v2f){-s, s}; }
__device__ __forceinline__ v2f swp(v2f a){ return __builtin_shufflevector(a, a, 1, 0); }
__device__ __forceinline__ v2f zero2(){ return (v2f){0.f, 0.f}; }

__device__ __forceinline__ int neigh(int s, int a){
    // dims (8,8,16,16): d3 bits[0:4), d2 bits[4:8), d1 bits[8:11), d0 bits[11:14)
    if (a == 3) return (s & ~15)        | ((s + 1)    & 15);
    if (a == 2) return (s & ~(15 << 4)) | ((s + 16)   & (15 << 4));
    if (a == 1) return (s & ~(7 << 8))  | ((s + 256)  & (7 << 8));
    return              (s & ~(7 << 11))| ((s + 2048) & (7 << 11));
}

// load one 9-v2f tile via 4x ds_read_b128 + 1x ds_read_b64
__device__ __forceinline__ void load_tile(v2f* tc, const v2f* tp){
    const float4* tp4 = (const float4*)tp;
    float4 q0 = tp4[0], q1 = tp4[1], q2 = tp4[2], q3 = tp4[3];
    tc[0] = (v2f){q0.x, q0.y}; tc[1] = (v2f){q0.z, q0.w};
    tc[2] = (v2f){q1.x, q1.y}; tc[3] = (v2f){q1.z, q1.w};
    tc[4] = (v2f){q2.x, q2.y}; tc[5] = (v2f){q2.z, q2.w};
    tc[6] = (v2f){q3.x, q3.y}; tc[7] = (v2f){q3.z, q3.w};
    tc[8] = tp[8];
}

__global__ __launch_bounds__(TPB, 2)
void gcm_fused(const float* __restrict__ xp,
               const float* __restrict__ wgt,
               float* __restrict__ outp)
{
    __shared__ alignas(16) v2f lt[SPB * TS2_SITE];
    __shared__ float wsm[NWGT];
    const v2f* x2 = (const v2f*)xp;
    v2f* o2 = (v2f*)outp;

    const int tid = threadIdx.x;
    const int g   = tid & 3;            // lane bits 0-1 -> shfl_xor reduction
    const int u   = (tid >> 2) & 3;     // output channel / phase1 axis
    const int sl  = tid >> 4;           // site within block
    const int s   = blockIdx.x * SPB + sl;

    // stage weights to LDS
    #pragma unroll 1
    for (int idx = tid; idx < NWGT; idx += TPB) wsm[idx] = wgt[idx];

    // ============ phase 1: one transport per thread: t[u*4+g] = U_u W_g(s+u^) U_u^+
    {
        v2f uc[9], wc[9];
        {
            const v2f* up = x2 + (s * 8 + u) * 9;
            #pragma unroll
            for (int e = 0; e < 9; e++) uc[e] = up[e];
        }
        const int sn = neigh(s, u);
        {
            const v2f* wp = x2 + (sn * 8 + 4 + g) * 9;
            #pragma unroll
            for (int e = 0; e < 9; e++) wc[e] = wp[e];
        }
        // T1 = U * W
        v2f t1[9];
        #pragma unroll
        for (int r = 0; r < 3; r++){
            #pragma unroll
            for (int k = 0; k < 3; k++){
                v2f acc = zero2();
                #pragma unroll
                for (int j = 0; j < 3; j++){
                    v2f a_ = uc[r*3+j], b_ = wc[j*3+k];
                    acc = pkfma(spl(a_.x), b_, acc);
                    acc = pkfma(np(a_.y), swp(b_), acc);
                }
                t1[r*3+k] = acc;
            }
        }
        // T = T1 * U^+ : T[r,k] = sum_j T1[r,j] * conj(U[k,j]); b128 writes
        v2f tt[9];
        #pragma unroll
        for (int r = 0; r < 3; r++){
            #pragma unroll
            for (int k = 0; k < 3; k++){
                v2f acc = zero2();
                #pragma unroll
                for (int j = 0; j < 3; j++){
                    v2f a_ = t1[r*3+j], b_ = uc[k*3+j];
                    acc = pkfma(pn(a_.x), b_, acc);
                    acc = pkfma(spl(a_.y), swp(b_), acc);
                }
                tt[r*3+k] = acc;
            }
        }
        v2f* dst = &lt[sl * TS2_SITE + (u * 4 + g) * TS_TILE];
        float4* dst4 = (float4*)dst;
        dst4[0] = make_float4(tt[0].x, tt[0].y, tt[1].x, tt[1].y);
        dst4[1] = make_float4(tt[2].x, tt[2].y, tt[3].x, tt[3].y);
        dst4[2] = make_float4(tt[4].x, tt[4].y, tt[5].x, tt[5].y);
        dst4[3] = make_float4(tt[6].x, tt[6].y, tt[7].x, tt[7].y);
        dst[8] = tt[8];
    }
    __syncthreads();

    // ============ phase 2 ============
    // pass-through copy of u channels (one quarter of lanes)
    if (g == 1){
        const v2f* src = x2 + (s * 8 + u) * 9;
        v2f* dst = o2 + (s * 8 + u) * 9;
        #pragma unroll
        for (int e = 0; e < 9; e++) dst[e] = src[e];
    }

    v2f M1[9], M2[9];
    #pragma unroll
    for (int e = 0; e < 9; e++){ M1[e] = zero2(); M2[e] = zero2(); }

    const float* wu  = wsm + u * 297;    // weight[u][v][w], stride 33 per v
    const float* wuA = wu + g * 33;      // v = g
    const float* wuB = wu + (4 + g) * 33;// v = 4+g
    const float* wu8 = wu + 8 * 33;      // v = 8

    const v2f* tbase = &lt[sl * TS2_SITE];

    // ---- main loop: M1/M2 only; w16 uniform across lanes (broadcast LDS reads)
    #pragma unroll 1
    for (int w16 = 0; w16 < 16; w16++){
        v2f tc[9];
        load_tile(tc, tbase + w16 * TS_TILE);
        float a1 = wuA[w16], b1 = wuA[16 + w16];
        float a2 = wuB[w16], b2 = wuB[16 + w16];
        #pragma unroll
        for (int i = 0; i < 3; i++){
            #pragma unroll
            for (int j = 0; j < 3; j++){
                const int e = i*3+j, eT = j*3+i;
                M1[e] = pkfma(spl(a1), tc[e],  M1[e]);
                M1[e] = pkfma(pn(b1),  tc[eT], M1[e]);
                M2[e] = pkfma(spl(a2), tc[e],  M2[e]);
                M2[e] = pkfma(pn(b2),  tc[eT], M2[e]);
            }
        }
    }

    // ---- cc: v=8 share over this thread's own quarter (w16 = 4g+it)
    v2f cc[9];
    #pragma unroll
    for (int e = 0; e < 9; e++) cc[e] = zero2();
    #pragma unroll 1
    for (int it = 0; it < 4; it++){
        const int w16 = g * 4 + it;
        v2f tc[9];
        load_tile(tc, tbase + w16 * TS_TILE);
        float c8 = wu8[w16], d8 = wu8[16 + w16];
        #pragma unroll
        for (int i = 0; i < 3; i++){
            #pragma unroll
            for (int j = 0; j < 3; j++){
                const int e = i*3+j, eT = j*3+i;
                cc[e] = pkfma(spl(c8), tc[e],  cc[e]);
                cc[e] = pkfma(pn(d8),  tc[eT], cc[e]);
            }
        }
    }

    // ---- identity (w=32) contributions to the diagonals
    {
        float c1 = wuA[32], c2 = wuB[32];
        M1[0].x += c1; M1[4].x += c1; M1[8].x += c1;
        M2[0].x += c2; M2[4].x += c2; M2[8].x += c2;
        if (g == 0){
            float e8 = wu8[32];
            cc[0].x += e8; cc[4].x += e8; cc[8].x += e8;
        }
    }

    // ---- wg loaded late (R12: early-issue neutral; late keeps loop pressure low)
    v2f wg[9];
    {
        const v2f* wp = x2 + (s * 8 + 4 + g) * 9;
        #pragma unroll
        for (int e = 0; e < 9; e++) wg[e] = wp[e];
    }

    // ---- epilogue: cc += w[g] @ M1 + w[g]^+ @ M2
    #pragma unroll
    for (int i = 0; i < 3; i++){
        #pragma unroll
        for (int k = 0; k < 3; k++){
            v2f acc = cc[i*3+k];
            #pragma unroll
            for (int j = 0; j < 3; j++){
                v2f a_ = wg[i*3+j];
                v2f m  = M1[j*3+k];
                acc = pkfma(spl(a_.x), m,      acc);   // (ax*mr, ax*mi)
                acc = pkfma(np(a_.y),  swp(m), acc);   // (-ay*mi, ay*mr)
            }
            #pragma unroll
            for (int j = 0; j < 3; j++){
                v2f b_ = wg[j*3+i];                    // conj-transpose source
                v2f m  = M2[j*3+k];
                acc = pkfma(spl(b_.x), m,      acc);   // (bx*mr, bx*mi)
                acc = pkfma(pn(b_.y),  swp(m), acc);   // (by*mi, -by*mr)
            }
            cc[i*3+k] = acc;
        }
    }

    // --- reduce partials over g (lane bits 0-1) and store
    #pragma unroll
    for (int e = 0; e < 9; e++){
        cc[e].x += __shfl_xor(cc[e].x, 1);
        cc[e].x += __shfl_xor(cc[e].x, 2);
        cc[e].y += __shfl_xor(cc[e].y, 1);
        cc[e].y += __shfl_xor(cc[e].y, 2);
    }
    if (g == 0){
        v2f* dst = o2 + (s * 8 + 4 + u) * 9;
        #pragma unroll
        for (int e = 0; e < 9; e++) dst[e] = cc[e];
    }
}

extern "C" void kernel_launch(void* const* d_in, const int* in_sizes, int n_in,
                              void* d_out, int out_size, void* d_ws, size_t ws_size,
                              hipStream_t stream)
{
    const float* x = (const float*)d_in[0];
    const float* w = (const float*)d_in[1];
    float* out = (float*)d_out;
    dim3 grid(NSITES / SPB);
    dim3 block(TPB);
    hipLaunchKernelGGL(gcm_fused, grid, block, 0, stream, x, w, out);
}